// Round 1
// baseline (801.284 us; speedup 1.0000x reference)
//
#include <hip/hip_runtime.h>
#include <hip/hip_bf16.h>

#define VOCAB 8000
#define HIDDEN 256
#define BATCH 32
#define SEQ 256
#define NPAD 8064              // 63 * 128, zero-padded vocab for GEMM staging
#define MROWS (SEQ * BATCH)    // 65536

typedef __attribute__((ext_vector_type(8))) short short8;   // 8 bf16 (4 VGPRs)
typedef __attribute__((ext_vector_type(4))) float floatx4;  // 4 f32 acc

// ---------- helpers ----------

__device__ __forceinline__ void async_copy16(const void* g, void* l) {
    __builtin_amdgcn_global_load_lds(
        (const __attribute__((address_space(1))) unsigned int*)g,
        (__attribute__((address_space(3))) unsigned int*)l, 16, 0, 0);
}

__device__ __forceinline__ unsigned short f32_to_bf16(float f) {
    unsigned int u = __float_as_uint(f);
    unsigned int lsb = (u >> 16) & 1u;
    u += 0x7fffu + lsb;            // round-to-nearest-even
    return (unsigned short)(u >> 16);
}

__device__ __forceinline__ float dot4(float4 a, float4 b) {
    return fmaf(a.x, b.x, fmaf(a.y, b.y, fmaf(a.z, b.z, a.w * b.w)));
}

// ---------- kernel 1: W_out f32 -> bf16, zero-padded to NPAD rows ----------

__global__ void __launch_bounds__(256) convw_kernel(const float* __restrict__ W_out,
                                                    unsigned short* __restrict__ Wbf) {
    int v = blockIdx.x;           // 0..NPAD-1
    int k = threadIdx.x;          // 0..255
    float f = (v < VOCAB) ? W_out[(size_t)v * HIDDEN + k] : 0.0f;
    Wbf[(size_t)v * HIDDEN + k] = f32_to_bf16(f);
}

// ---------- kernel 2: embedding gather  xp[(s*32+b)*256+h] = W_ih[h, X[b,s]] + b_ih[h] ----------

__global__ void __launch_bounds__(256) gather_kernel(const int* __restrict__ X,
                                                     const float* __restrict__ W_ih,
                                                     const float* __restrict__ b_ih,
                                                     float* __restrict__ xp) {
    int n = blockIdx.x;           // n = s*BATCH + b, 0..8191
    int h = threadIdx.x;          // 0..255
    int s = n >> 5;
    int b = n & 31;
    int tok = X[b * SEQ + s];
    xp[(size_t)n * HIDDEN + h] = W_ih[(size_t)h * VOCAB + tok] + b_ih[h];
}

// ---------- kernel 3: Elman recurrence, one block per batch element ----------
// 1024 threads: i = tid&255 (hidden out), q = tid>>8 (K-quarter). W_hh row segment
// lives in registers (64 f32/thread). h in LDS (wave-uniform broadcast reads).

__global__ void __launch_bounds__(1024) rnn_kernel(const float* __restrict__ xp,
                                                   const float* __restrict__ h0,
                                                   const float* __restrict__ W_hh,
                                                   const float* __restrict__ b_hh,
                                                   unsigned short* __restrict__ Ybf,
                                                   float* __restrict__ h_last) {
    __shared__ __align__(16) float h_lds[HIDDEN];
    __shared__ float part_lds[3 * HIDDEN];

    const int b   = blockIdx.x;
    const int tid = threadIdx.x;
    const int i   = tid & 255;
    const int q   = tid >> 8;

    // load W_hh[i][q*64 .. q*64+63] into registers
    float4 w4[16];
    const float4* wrow = (const float4*)(W_hh + (size_t)i * HIDDEN + q * 64);
#pragma unroll
    for (int c = 0; c < 16; ++c) w4[c] = wrow[c];

    float bh = 0.f, x_cur = 0.f;
    if (q == 0) {
        bh = b_hh[i];
        h_lds[i] = h0[b * HIDDEN + i];
        x_cur = xp[(size_t)(0 * BATCH + b) * HIDDEN + i];
    }
    __syncthreads();

    for (int s = 0; s < SEQ; ++s) {
        const float4* hv = (const float4*)(h_lds + q * 64);
        float a0 = 0.f, a1 = 0.f, a2 = 0.f, a3 = 0.f;
#pragma unroll
        for (int c = 0; c < 16; c += 4) {
            a0 += dot4(w4[c + 0], hv[c + 0]);
            a1 += dot4(w4[c + 1], hv[c + 1]);
            a2 += dot4(w4[c + 2], hv[c + 2]);
            a3 += dot4(w4[c + 3], hv[c + 3]);
        }
        float partial = (a0 + a1) + (a2 + a3);

        // prefetch next x_t while others finish
        float x_next = 0.f;
        if (q == 0 && s + 1 < SEQ)
            x_next = xp[(size_t)((s + 1) * BATCH + b) * HIDDEN + i];

        if (q > 0) part_lds[(q - 1) * HIDDEN + i] = partial;
        __syncthreads();

        if (q == 0) {
            float acc = partial + part_lds[i] + part_lds[HIDDEN + i] +
                        part_lds[2 * HIDDEN + i] + x_cur + bh;
            float hn = tanhf(acc);
            h_lds[i] = hn;
            Ybf[(size_t)(s * BATCH + b) * HIDDEN + i] = f32_to_bf16(hn);
            if (s == SEQ - 1) h_last[b * HIDDEN + i] = hn;
            x_cur = x_next;
        }
        __syncthreads();
    }
}

// ---------- kernel 4: out = Y(bf16) @ Wout(bf16)^T + b_out  (M=65536, N=8000, K=256) ----------
// 128x128 tile, BK=32, 4 waves (2x2), each wave 64x64 via 4x4 MFMA 16x16x32 tiles.

__global__ void __launch_bounds__(256) gemm_kernel(const unsigned short* __restrict__ Ybf,
                                                   const unsigned short* __restrict__ Wbf,
                                                   const float* __restrict__ b_out,
                                                   float* __restrict__ out) {
    __shared__ __align__(16) short sA[128 * 32];
    __shared__ __align__(16) short sB[128 * 32];

    const int tid  = threadIdx.x;
    const int lane = tid & 63;
    const int wave = tid >> 6;
    const int wm   = wave >> 1;
    const int wn   = wave & 1;
    const int l16  = lane & 15;
    const int lq   = lane >> 4;

    const int m0 = blockIdx.y * 128;
    const int n0 = blockIdx.x * 128;

    floatx4 acc[4][4] = {};

    // staging map: 512 chunks of 16B per tile, 2 chunks/thread
    const int chunk0 = tid;
    const int chunk1 = 256 + tid;
    const int rowA0 = chunk0 >> 2, kc0 = chunk0 & 3;
    const int rowA1 = chunk1 >> 2, kc1 = chunk1 & 3;

    for (int k0 = 0; k0 < HIDDEN; k0 += 32) {
        async_copy16(Ybf + (size_t)(m0 + rowA0) * HIDDEN + k0 + kc0 * 8, sA + chunk0 * 8);
        async_copy16(Ybf + (size_t)(m0 + rowA1) * HIDDEN + k0 + kc1 * 8, sA + chunk1 * 8);
        async_copy16(Wbf + (size_t)(n0 + rowA0) * HIDDEN + k0 + kc0 * 8, sB + chunk0 * 8);
        async_copy16(Wbf + (size_t)(n0 + rowA1) * HIDDEN + k0 + kc1 * 8, sB + chunk1 * 8);
        __syncthreads();   // compiler drains vmcnt(0) before s_barrier

        short8 afrag[4], bfrag[4];
#pragma unroll
        for (int t = 0; t < 4; ++t) {
            afrag[t] = *(const short8*)&sA[(wm * 64 + t * 16 + l16) * 32 + lq * 8];
            bfrag[t] = *(const short8*)&sB[(wn * 64 + t * 16 + l16) * 32 + lq * 8];
        }
#pragma unroll
        for (int tm = 0; tm < 4; ++tm)
#pragma unroll
            for (int tn = 0; tn < 4; ++tn)
                acc[tm][tn] = __builtin_amdgcn_mfma_f32_16x16x32_bf16(
                    afrag[tm], bfrag[tn], acc[tm][tn], 0, 0, 0);
        __syncthreads();
    }

    // epilogue: C/D layout col=lane&15 (n), row=(lane>>4)*4+reg (m)
#pragma unroll
    for (int tn = 0; tn < 4; ++tn) {
        int n = n0 + wn * 64 + tn * 16 + l16;
        if (n < VOCAB) {
            float bo = b_out[n];
#pragma unroll
            for (int tm = 0; tm < 4; ++tm) {
                int mbase = m0 + wm * 64 + tm * 16 + lq * 4;
#pragma unroll
                for (int r = 0; r < 4; ++r) {
                    out[(size_t)(mbase + r) * VOCAB + n] = acc[tm][tn][r] + bo;
                }
            }
        }
    }
}

// ---------- launch ----------

extern "C" void kernel_launch(void* const* d_in, const int* in_sizes, int n_in,
                              void* d_out, int out_size, void* d_ws, size_t ws_size,
                              hipStream_t stream) {
    const int*   X     = (const int*)d_in[0];
    const float* h0    = (const float*)d_in[1];
    const float* W_ih  = (const float*)d_in[2];
    const float* b_ih  = (const float*)d_in[3];
    const float* W_hh  = (const float*)d_in[4];
    const float* b_hh  = (const float*)d_in[5];
    const float* W_out = (const float*)d_in[6];
    const float* b_out = (const float*)d_in[7];

    float* out    = (float*)d_out;
    float* h_last = out + (size_t)MROWS * VOCAB;

    // workspace layout
    char* ws = (char*)d_ws;
    float*          xp  = (float*)ws;                          //  8,388,608 B
    unsigned short* Ybf = (unsigned short*)(ws + 8388608);     // 33,554,432 B
    unsigned short* Wbf = (unsigned short*)(ws + 41943040);    //  4,128,768 B  (total ~44 MB)

    hipLaunchKernelGGL(convw_kernel,  dim3(NPAD),     dim3(256),  0, stream, W_out, Wbf);
    hipLaunchKernelGGL(gather_kernel, dim3(SEQ * BATCH), dim3(256), 0, stream, X, W_ih, b_ih, xp);
    hipLaunchKernelGGL(rnn_kernel,    dim3(BATCH),    dim3(1024), 0, stream, xp, h0, W_hh, b_hh, Ybf, h_last);
    hipLaunchKernelGGL(gemm_kernel,   dim3(NPAD / 128, MROWS / 128), dim3(256), 0, stream,
                       Ybf, Wbf, b_out, out);
}